// Round 5
// baseline (162.292 us; speedup 1.0000x reference)
//
#include <hip/hip_runtime.h>

// CAM_43344809951340: per-sample symmetric outer-product tanh attention.
// tanh(u) = 1 - 2/(1+e^{2u}); fold 2*SCALE*log2(e) into scaled av (xc),
// fold -2W into weights, hoist sum(W).
//
// Symmetry T[i][j]=T[j][i]: diagonal walk k=31..0, lane r computes
// p = 1/(1+exp2(x_r * xc_{r+k})) once per unordered pair.
//   own-row:  p * (-2 W_{row_r}[(r+k)&63])          (wo from LDS table)
//   mirror:   deposit p * (-2 W_{row_{r+k}}[r])     (wd from table) into a
//             traveling accumulator t; t rotates +1 lane/step via DPP
//             WAVE_ROR1 (0x13C: D[i]=S[(i-1)&63], values move to HIGHER
//             lanes -- direction verified against LLVM AtomicOptimizer's
//             WAVE_SHR1 exclusive-scan semantics), so a deposit at step k
//             lands at lane r+k after its k remaining rotations.
// The av operand travels the same way in a register.
// Weights for step pairs packed as float4 -> 15 ds_read_b128 + 1 b64/sample.

__device__ __forceinline__ float wave_ror1_f32(float v) {
    // D[i] = S[(i-1) & 63] — full-wave rotate toward higher lanes
    return __int_as_float(__builtin_amdgcn_update_dpp(
        __float_as_int(v), __float_as_int(v), 0x13C, 0xF, 0xF, false));
}

__global__ __launch_bounds__(512, 8) void cam_kernel(
    const float* __restrict__ f1,
    const float* __restrict__ f2,
    const float* __restrict__ Wca,
    const float* __restrict__ Wcv,
    float* __restrict__ out,
    int B)
{
    // 2 * SCALE * log2(e) = 0.25 * 1.4426950408889634
    constexpr float C = 0.3606737602222409f;

    // Pair table: kp=0..14 covers steps k1=31-2kp (.x=wo,.y=wd) and
    //             k0=30-2kp (.z=wo,.w=wd).   wo(k)=-2*W_sel[(ln+k)&63],
    //             wd(k)=-2*W_{half((ln+k)&63)}[ln].
    __shared__ __align__(16) float4 s_P4[2][15][64];   // 30 KB
    __shared__ __align__(8)  float2 s_P1[2][64];       // k=1 weights, 1 KB
    __shared__ float s_wsum[2];

    const int tid  = threadIdx.x;
    const int lane = tid & 63;

    for (int idx = tid; idx < 2048; idx += 512) {      // 2*16*64 slots, kp<15 real
        const int sel = idx >> 10;
        const int kp  = (idx >> 6) & 15;
        const int ln  = idx & 63;
        if (kp < 15) {
            const int k1 = 31 - 2 * kp, k0 = 30 - 2 * kp;
            const int j1 = (ln + k1) & 63, j0 = (ln + k0) & 63;
            const float* Ws = sel ? Wcv : Wca;
            s_P4[sel][kp][ln] = make_float4(
                -2.0f * Ws[j1], -2.0f * ((j1 < 32) ? Wca : Wcv)[ln],
                -2.0f * Ws[j0], -2.0f * ((j0 < 32) ? Wca : Wcv)[ln]);
        }
    }
    if (tid < 128) {                                   // k=1 table + row sums
        const int sel = tid >> 6;
        const int j = (lane + 1) & 63;
        s_P1[sel][lane] = make_float2(
            -2.0f * (sel ? Wcv : Wca)[j],
            -2.0f * ((j < 32) ? Wca : Wcv)[lane]);
        float s = (sel ? Wcv : Wca)[lane];
        #pragma unroll
        for (int off = 32; off > 0; off >>= 1) s += __shfl_xor(s, off, 64);
        if (lane == 0) s_wsum[sel] = s;
    }
    __syncthreads();

    const int sel = lane >> 5;                         // 0: audio, 1: visual half
    const float wsum = s_wsum[sel];
    const float4* __restrict__ P4p = &s_P4[sel][0][lane];   // pair kp at P4p[kp*64]
    const float2* __restrict__ P1p = &s_P1[sel][lane];
    const float* __restrict__ fbase = sel ? f2 : f1;
    const int col = lane & 31;

    const float w0  = -2.0f * (sel ? Wcv : Wca)[lane];        // k=0 (diagonal)
    const float w32 = -2.0f * (sel ? Wcv : Wca)[lane ^ 32];   // k=32
    const int idx31 = ((lane + 31) & 63) << 2;         // bpermute byte indices
    const int idx32 = (lane ^ 32) << 2;

    const int gw     = (blockIdx.x * 512 + tid) >> 6;
    const int stride = gridDim.x << 3;                 // total waves

    int b = gw;
    if (b >= B) return;                                // wave-uniform
    float x = fbase[b * 32 + col];

    while (b < B) {
        const int bn = b + stride;
        float xn = 0.0f;
        if (bn < B) xn = fbase[bn * 32 + col];         // prefetch next sample

        const float xc = x * C;
        float a = __int_as_float(                      // xc_{(r+31)&63}
            __builtin_amdgcn_ds_bpermute(idx31, __float_as_int(xc)));
        const float a32 = __int_as_float(              // xc_{r^32}
            __builtin_amdgcn_ds_bpermute(idx32, __float_as_int(xc)));

        // k=32: both lanes of the pair compute it as own-row (no deposit)
        float own1 = __builtin_amdgcn_rcpf(1.0f + __builtin_amdgcn_exp2f(x * a32)) * w32;
        // k=0 diagonal: independent of the a-chain, schedules early
        float own0 = __builtin_amdgcn_rcpf(1.0f + __builtin_amdgcn_exp2f(x * xc)) * w0;

        float t = 0.0f;                                // traveling mirror acc
        #pragma unroll
        for (int kp = 0; kp < 15; ++kp) {              // k = 31..2
            const float4 w4 = P4p[kp * 64];            // ds_read_b128, imm offset
            float p = __builtin_amdgcn_rcpf(1.0f + __builtin_amdgcn_exp2f(x * a));
            own0 = fmaf(p, w4.x, own0);
            t = fmaf(p, w4.y, t);
            t = wave_ror1_f32(t);
            a = wave_ror1_f32(a);
            p = __builtin_amdgcn_rcpf(1.0f + __builtin_amdgcn_exp2f(x * a));
            own1 = fmaf(p, w4.z, own1);
            t = fmaf(p, w4.w, t);
            t = wave_ror1_f32(t);
            a = wave_ror1_f32(a);
        }
        {   // k = 1
            const float2 w2 = P1p[0];                  // ds_read_b64
            const float p = __builtin_amdgcn_rcpf(1.0f + __builtin_amdgcn_exp2f(x * a));
            own0 = fmaf(p, w2.x, own0);
            t = fmaf(p, w2.y, t);
            t = wave_ror1_f32(t);                      // final roll: k=1 deposit lands
        }

        float h = wsum + x + own0 + own1 + t;
        h = fmaxf(h, 0.0f) * 0.1f;
        out[b * 64 + lane] = h;

        b = bn;
        x = xn;
    }
}

extern "C" void kernel_launch(void* const* d_in, const int* in_sizes, int n_in,
                              void* d_out, int out_size, void* d_ws, size_t ws_size,
                              hipStream_t stream) {
    const float* f1  = (const float*)d_in[0];
    const float* f2  = (const float*)d_in[1];
    const float* Wca = (const float*)d_in[2];
    const float* Wcv = (const float*)d_in[3];
    float* out = (float*)d_out;

    const int B = in_sizes[0] / 32;
    int blocks = (B + 7) / 8;           // 8 waves/block (512 thr)
    if (blocks > 1024) blocks = 1024;   // 4 blocks/CU (31 KB LDS) = 32 waves/CU
    if (blocks < 1) blocks = 1;

    cam_kernel<<<blocks, 512, 0, stream>>>(f1, f2, Wca, Wcv, out, B);
}

// Round 6
// 140.506 us; speedup vs baseline: 1.1551x; 1.1551x over previous
//
#include <hip/hip_runtime.h>

// CAM_43344809951340: per-sample symmetric outer-product tanh attention.
// tanh(u) = 1 - 2/(1+e^{2u}); fold 2*SCALE*log2(e) into scaled av (xc),
// fold -2W into weights, hoist sum(W).
//
// Symmetric diagonal walk (validated R5, absmax 9.8e-4): step k=31..1,
// lane r computes p = 1/(1+exp2(x_r * xc_{r+k})) once per unordered pair:
//   own-row:  p * wo_k,  wo_k = -2 W_{row_r}[(r+k)&63]   (LDS float2 .x)
//   mirror:   t = ror1(fma(p, wd_k, t)), wd_k = -2 W_{row_{r+k}}[r] (.y);
//             WAVE_ROR1 (0x13C) moves values toward higher lanes, so a
//             deposit at step k lands at lane r+k after its k rotations.
//   av operand a travels by ror1 from xc_{r+31} down to xc_{r+1}.
// k=0 (diagonal) and k=32 (pair computes both sides as own-row) special.
//
// NEW vs R5: TWO samples (b, b+1) per wave iteration — independent chains
// interleave to fill exp/rcp/DPP latency bubbles (R5 VALUBusy was 59%),
// and each per-step float2 weight read serves both samples.

__device__ __forceinline__ float wave_ror1_f32(float v) {
    // D[i] = S[(i-1) & 63] — values move toward higher lanes
    return __int_as_float(__builtin_amdgcn_update_dpp(
        __float_as_int(v), __float_as_int(v), 0x13C, 0xF, 0xF, false));
}

__device__ __forceinline__ float sig2(float x, float a) {
    // 1/(1 + exp2(x*a))
    return __builtin_amdgcn_rcpf(1.0f + __builtin_amdgcn_exp2f(x * a));
}

__global__ __launch_bounds__(256, 8) void cam_kernel(
    const float* __restrict__ f1,
    const float* __restrict__ f2,
    const float* __restrict__ Wca,
    const float* __restrict__ Wcv,
    float* __restrict__ out,
    int B)
{
    // 2 * SCALE * log2(e) = 0.25 * 1.4426950408889634
    constexpr float C = 0.3606737602222409f;

    // s_P[sel][k][ln] = { -2*W_sel[(ln+k)&63], -2*W_{half((ln+k)&63)}[ln] }
    __shared__ __align__(16) float2 s_P[2][32][64];    // 16 KB
    __shared__ float s_wsum[2];

    const int tid  = threadIdx.x;
    const int lane = tid & 63;

    for (int idx = tid; idx < 2 * 32 * 64; idx += 256) {
        const int sel = idx >> 11;
        const int k   = (idx >> 6) & 31;
        const int ln  = idx & 63;
        const int j   = (ln + k) & 63;
        s_P[sel][k][ln] = make_float2(
            -2.0f * (sel ? Wcv : Wca)[j],
            -2.0f * ((j < 32) ? Wca : Wcv)[ln]);
    }
    if (tid < 128) {                                   // row sums (waves 0,1)
        const int sel = tid >> 6;
        float s = (sel ? Wcv : Wca)[lane];
        #pragma unroll
        for (int off = 32; off > 0; off >>= 1) s += __shfl_xor(s, off, 64);
        if (lane == 0) s_wsum[sel] = s;
    }
    __syncthreads();

    const int sel = lane >> 5;                         // 0: audio, 1: visual half
    const float wsum = s_wsum[sel];
    const float2* __restrict__ Pp = &s_P[sel][0][lane];    // step k at Pp[k*64]
    const float* __restrict__ fbase = sel ? f2 : f1;
    const int col = lane & 31;

    const float w0  = -2.0f * (sel ? Wcv : Wca)[lane];        // k=0 (diagonal)
    const float w32 = -2.0f * (sel ? Wcv : Wca)[lane ^ 32];   // k=32
    const int idx31 = ((lane + 31) & 63) << 2;         // bpermute byte indices
    const int idx32 = (lane ^ 32) << 2;

    const int gw     = (blockIdx.x * 256 + tid) >> 6;
    const int stride = (gridDim.x << 2) * 2;           // 2 samples per wave/iter

    int b = gw * 2;
    if (b >= B) return;                                // wave-uniform
    float xA = fbase[b * 32 + col];
    float xB = (b + 1 < B) ? fbase[(b + 1) * 32 + col] : 0.0f;

    while (b < B) {
        const int bn = b + stride;
        float xnA = 0.0f, xnB = 0.0f;
        if (bn < B) {                                  // prefetch next pair
            xnA = fbase[bn * 32 + col];
            if (bn + 1 < B) xnB = fbase[(bn + 1) * 32 + col];
        }

        const float xcA = xA * C;
        const float xcB = xB * C;
        float aA = __int_as_float(
            __builtin_amdgcn_ds_bpermute(idx31, __float_as_int(xcA)));
        float aB = __int_as_float(
            __builtin_amdgcn_ds_bpermute(idx31, __float_as_int(xcB)));
        const float a32A = __int_as_float(
            __builtin_amdgcn_ds_bpermute(idx32, __float_as_int(xcA)));
        const float a32B = __int_as_float(
            __builtin_amdgcn_ds_bpermute(idx32, __float_as_int(xcB)));

        // k=0 diagonal + k=32 (both lanes own-row), per sample
        float own0A = sig2(xA, xcA)  * w0;
        float own0B = sig2(xB, xcB)  * w0;
        float own1A = sig2(xA, a32A) * w32;
        float own1B = sig2(xB, a32B) * w32;

        float tA = 0.0f, tB = 0.0f;                    // traveling mirror accs
        #pragma unroll
        for (int k = 31; k >= 1; --k) {
            const float2 w2 = Pp[k * 64];              // ds_read_b64, imm offset
            const float pA = sig2(xA, aA);
            const float pB = sig2(xB, aB);
            if (k & 1) { own0A = fmaf(pA, w2.x, own0A); own0B = fmaf(pB, w2.x, own0B); }
            else       { own1A = fmaf(pA, w2.x, own1A); own1B = fmaf(pB, w2.x, own1B); }
            tA = wave_ror1_f32(fmaf(pA, w2.y, tA));
            aA = wave_ror1_f32(aA);
            tB = wave_ror1_f32(fmaf(pB, w2.y, tB));
            aB = wave_ror1_f32(aB);
        }
        // after the k=1 iteration each deposit has had exactly k rotations

        const float hA = fmaxf(wsum + xA + own0A + own1A + tA, 0.0f) * 0.1f;
        const float hB = fmaxf(wsum + xB + own0B + own1B + tB, 0.0f) * 0.1f;
        out[b * 64 + lane] = hA;
        if (b + 1 < B) out[(b + 1) * 64 + lane] = hB;

        b = bn;
        xA = xnA;
        xB = xnB;
    }
}

extern "C" void kernel_launch(void* const* d_in, const int* in_sizes, int n_in,
                              void* d_out, int out_size, void* d_ws, size_t ws_size,
                              hipStream_t stream) {
    const float* f1  = (const float*)d_in[0];
    const float* f2  = (const float*)d_in[1];
    const float* Wca = (const float*)d_in[2];
    const float* Wcv = (const float*)d_in[3];
    float* out = (float*)d_out;

    const int B = in_sizes[0] / 32;
    const int pairs = (B + 1) / 2;
    int blocks = (pairs + 3) / 4;       // 4 waves/block, 1 pair/wave minimum
    if (blocks > 2048) blocks = 2048;   // 8 blocks/CU (16.5 KB LDS, 8 waves/SIMD)
    if (blocks < 1) blocks = 1;

    cam_kernel<<<blocks, 256, 0, stream>>>(f1, f2, Wca, Wcv, out, B);
}